// Round 10
// baseline (261.152 us; speedup 1.0000x reference)
//
#include <hip/hip_runtime.h>
#include <hip/hip_fp16.h>

// NNConv on MI355X. msg[E x 32] = Z[E x 4096] @ w2r[4096 x 32],
// Z[e, c*32+i] = h[e,c]*xs[e,i] built on the fly in fp16 A-fragments.
// Round 20: LDS-STAGED w2 slices. R11/R13/R17/R19 ledger isolates the
// ~900 idle cy/column to the inner-loop global B-column loads: ~3100
// waves queue on the SAME 256 KB of L2 lines (~25 MB outstanding), so
// effective latency >> any affordable register prefetch depth. Fix:
// 256-thr blocks (4 waves x 128 edges = 512 edges, grid 782) stage each
// 64 KB w2 slice into LDS via global_load_lds (16 issues/wave,
// overlapped with phase1 MFMAs, 1 barrier), then compute reads
// ds_read_b128 (deterministic ~120cy, per-CU, compiler-hoistable).
// 8 barriers/block, each amortized over ~6k cy of compute (not R10's
// per-8KB drain). Reg-resident h via permlane32_swap (R19, verified).
// __launch_bounds__(256,1): empirical cap = 256/arg = 256 VGPR.
// w2 L2 traffic: 782 x 256 KB = 200 MB staged once per block.

#define NN 25000
#define EE 400000

typedef _Float16 f16x8 __attribute__((ext_vector_type(8)));
typedef float    f32x16 __attribute__((ext_vector_type(16)));
typedef unsigned u32x2  __attribute__((ext_vector_type(2)));

__device__ __forceinline__ void async16(const void* g, void* l) {
    // one 16B element per lane; LDS dest = wave-uniform base + lane*16
    __builtin_amdgcn_global_load_lds(
        (const __attribute__((address_space(1))) unsigned int*)g,
        (__attribute__((address_space(3))) unsigned int*)l, 16, 0, 0);
}

// half-exchange: a = half0-lane values (rows base,base+1), y = half1-lane
// values (rows base+4,base+5), for every lane's own edge column (l&31).
__device__ __forceinline__ void swapHalves(unsigned u, int half,
                                           unsigned& a, unsigned& y) {
#if __has_builtin(__builtin_amdgcn_permlane32_swap)
    u32x2 rr = __builtin_amdgcn_permlane32_swap(u, u, false, false);
    a = rr.x;
    y = rr.y;
#else
    unsigned p = (unsigned)__shfl_xor((int)u, 32, 64);
    a = half ? p : u;
    y = half ? u : p;
#endif
}

// ---------------- launch 1: pack w1/w2/b2 + out = x@root + bias ----------------
__global__ __launch_bounds__(256) void prep_final_kernel(
    const float* __restrict__ x, const float* __restrict__ root,
    const float* __restrict__ bias,
    const float* __restrict__ w1, const float* __restrict__ w2,
    const float* __restrict__ b2,
    _Float16* __restrict__ w2p, _Float16* __restrict__ w1p, _Float16* __restrict__ b2p,
    float* __restrict__ out)
{
    const int t = blockIdx.x * 256 + threadIdx.x;

    if (t < 131072) {
        int j = t & 7, lane = (t >> 3) & 63, ih = (t >> 9) & 1, c = t >> 10;
        w2p[t] = (_Float16)w2[c * 1024 + (ih * 16 + ((lane >> 5) << 3) + j) * 32 + (lane & 31)];
    } else if (t < 135168) {
        int u = t - 131072;
        int j = u & 7, lane = (u >> 3) & 63, kk = (u >> 9) & 1, r = u >> 10;
        w1p[u] = (_Float16)w1[(kk * 16 + ((lane >> 5) << 3) + j) * 128 + r * 32 + (lane & 31)];
    } else if (t < 136192) {
        int u = t - 135168;
        int j = u & 7, lane = (u >> 3) & 63, ih = u >> 9;
        b2p[u] = (_Float16)b2[(ih * 16 + ((lane >> 5) << 3) + j) * 32 + (lane & 31)];
    }

    int n = t >> 5, o = t & 31;
    float acc = bias[o];
    const float* xr = x + (n << 5);
#pragma unroll
    for (int i = 0; i < 32; ++i)
        acc = fmaf(xr[i], root[(i << 5) + o], acc);
    out[t] = acc;
}

// ---------------- launch 2: edge kernel (LDS-staged w2, reg-resident h) ----------------
// 256 thr = 4 waves x 128 edges (4 groups of 32) = 512 edges/block, grid 782.
__global__ __launch_bounds__(256, 1) void edge_kernel(
    const float*    __restrict__ x,
    const int*      __restrict__ ei,
    const float*    __restrict__ ea,
    const float*    __restrict__ b1,
    const _Float16* __restrict__ w2p,
    const _Float16* __restrict__ w1p,
    const _Float16* __restrict__ b2p,
    float* __restrict__ out)
{
    __shared__ __align__(16) _Float16 w2s[32768];   // 64 KB: one 32-col slice

    const int t    = threadIdx.x;
    const int w    = t >> 6;
    const int lane = t & 63;
    const int l    = lane & 31;
    const int half = lane >> 5;

    const int  ebraw = blockIdx.x * 512 + w * 128;
    const bool live  = (ebraw + 128) <= EE;        // wave-uniform
    const int  ebw   = live ? ebraw : (EE - 128);

    union u8h { f16x8 v; __half2 h2[4]; };

    // ---- stage slice r (64 KB) into LDS: 16 x 1KB issues per wave ----
    const char* w2g = (const char*)w2p;
    auto stageSlice = [&](int r) {
#pragma unroll
        for (int s = 0; s < 16; ++s) {
            const int off = w * 16384 + s * 1024;            // wave-uniform
            async16(w2g + (size_t)r * 65536 + off + lane * 16,
                    (void*)((char*)w2s + off));
        }
    };

    // ---- persistent edge-attr fragments (fp16), 4 groups; read ONCE ----
    u8h eaf[4][2];
#pragma unroll
    for (int g = 0; g < 4; ++g)
#pragma unroll
        for (int kk = 0; kk < 2; ++kk) {
            const float* p = ea + (size_t)(ebw + g * 32 + l) * 32 + kk * 16 + half * 8;
            float4 a0 = *(const float4*)p;
            float4 a1 = *(const float4*)(p + 4);
            eaf[g][kk].h2[0] = __float22half2_rn(make_float2(a0.x, a0.y));
            eaf[g][kk].h2[1] = __float22half2_rn(make_float2(a0.z, a0.w));
            eaf[g][kk].h2[2] = __float22half2_rn(make_float2(a1.x, a1.y));
            eaf[g][kk].h2[3] = __float22half2_rn(make_float2(a1.z, a1.w));
        }

    // ---- gather xs rows (fp16 pairs) for 4 groups ----
    __half2 xs[4][8];
#pragma unroll
    for (int g = 0; g < 4; ++g) {
        int s = ei[ebw + g * 32 + l];
#pragma unroll
        for (int ih = 0; ih < 2; ++ih) {
            float4 a0 = *(const float4*)(x + s * 32 + ih * 16 + half * 8);
            float4 a1 = *(const float4*)(x + s * 32 + ih * 16 + half * 8 + 4);
            xs[g][ih*4+0] = __float22half2_rn(make_float2(a0.x, a0.y));
            xs[g][ih*4+1] = __float22half2_rn(make_float2(a0.z, a0.w));
            xs[g][ih*4+2] = __float22half2_rn(make_float2(a1.x, a1.y));
            xs[g][ih*4+3] = __float22half2_rn(make_float2(a1.z, a1.w));
        }
    }

    f32x16 acc[4];
#pragma unroll
    for (int g = 0; g < 4; ++g)
#pragma unroll
        for (int i = 0; i < 16; ++i) acc[g][i] = 0.f;

    // h slice own-half pairs (R19-verified layout): hpk[g][jj] = channels
    // (base(jj)+4*half, +1), base(jj) = (2jj&3) + ((2jj>>2)<<3).
    __half2 hpk[4][8];

    auto phase1 = [&](int r) {
        f16x8 w1f0 = *(const f16x8*)(w1p + ((r * 2 + 0) * 64 + lane) * 8);
        f16x8 w1f1 = *(const f16x8*)(w1p + ((r * 2 + 1) * 64 + lane) * 8);
#pragma unroll
        for (int g = 0; g < 4; ++g) {
            f32x16 h;
#pragma unroll
            for (int i = 0; i < 16; ++i) h[i] = 0.f;
            h = __builtin_amdgcn_mfma_f32_32x32x16_f16(w1f0, eaf[g][0].v, h, 0, 0, 0);
            h = __builtin_amdgcn_mfma_f32_32x32x16_f16(w1f1, eaf[g][1].v, h, 0, 0, 0);
#pragma unroll
            for (int jj = 0; jj < 8; ++jj) {
                int i0 = 2 * jj;
                int r0 = (i0 & 3) + ((i0 >> 2) << 3) + (half << 2);  // verified C/D map
                hpk[g][jj] = __float22half2_rn(make_float2(
                    fmaxf(h[i0]     + b1[r * 32 + r0],     0.f),
                    fmaxf(h[i0 + 1] + b1[r * 32 + r0 + 1], 0.f)));
            }
        }
    };

    __half2 Ac[4][2], Yc[4][2];        // swap cache (R19-verified mapping)

    // one column (local index lcol in slice): B-frags from LDS, 8 MFMAs
    auto colMFMA = [&](const __half2 (&C)[4][2], int dd, bool hi, int lcol) {
        __half2 d[4];
#pragma unroll
        for (int g = 0; g < 4; ++g)
            d[g] = __half2half2(hi ? __high2half(C[g][dd]) : __low2half(C[g][dd]));
#pragma unroll
        for (int ih = 0; ih < 2; ++ih) {
            f16x8 bfr = *(const f16x8*)&w2s[lcol * 1024 + ih * 512 + lane * 8];
#pragma unroll
            for (int g = 0; g < 4; ++g) {
                u8h A;
#pragma unroll
                for (int p = 0; p < 4; ++p)
                    A.h2[p] = __hmul2(d[g], xs[g][ih * 4 + p]);   // v_pk_mul_f16
                acc[g] = __builtin_amdgcn_mfma_f32_32x32x16_f16(A.v, bfr, acc[g], 0, 0, 0);
            }
        }
    };

    // ---- main loop: 4 slices; stage -> (phase1 overlaps DMA) -> barrier
    // -> 32 columns from LDS. No global loads inside the column loop. ----
#pragma unroll 1
    for (int r = 0; r < 4; ++r) {
        if (r > 0) __syncthreads();    // all waves done reading slice r-1
        stageSlice(r);                 // DMA in flight...
        phase1(r);                     // ...overlapped with MFMA/VALU
        __syncthreads();               // drains vmcnt: slice resident
#pragma unroll
        for (int q = 0; q < 8; ++q) {
            const int c0 = q * 4;
            if ((q & 1) == 0) {
#pragma unroll
                for (int g = 0; g < 4; ++g)
#pragma unroll
                    for (int dd = 0; dd < 2; ++dd) {
                        unsigned a, y;
                        swapHalves(__builtin_bit_cast(unsigned, hpk[g][q + dd]),
                                   half, a, y);
                        Ac[g][dd] = __builtin_bit_cast(__half2, a);
                        Yc[g][dd] = __builtin_bit_cast(__half2, y);
                    }
                colMFMA(Ac, 0, false, c0 + 0);
                colMFMA(Ac, 0, true,  c0 + 1);
                colMFMA(Ac, 1, false, c0 + 2);
                colMFMA(Ac, 1, true,  c0 + 3);
            } else {
                colMFMA(Yc, 0, false, c0 + 0);
                colMFMA(Yc, 0, true,  c0 + 1);
                colMFMA(Yc, 1, false, c0 + 2);
                colMFMA(Yc, 1, true,  c0 + 3);
            }
        }
    }

    // ---- b2 contribution: extra K-step with h == 1 (A-fragment = xs) ----
#pragma unroll
    for (int ih = 0; ih < 2; ++ih) {
        f16x8 bfr = *(const f16x8*)(b2p + (ih * 64 + lane) * 8);
#pragma unroll
        for (int g = 0; g < 4; ++g) {
            u8h A;
#pragma unroll
            for (int p = 0; p < 4; ++p) A.h2[p] = xs[g][ih * 4 + p];
            acc[g] = __builtin_amdgcn_mfma_f32_32x32x16_f16(A.v, bfr, acc[g], 0, 0, 0);
        }
    }

    // ---- scatter-add into out (base written by launch 1) ----
    if (live) {
#pragma unroll
        for (int g = 0; g < 4; ++g)
#pragma unroll
            for (int i = 0; i < 16; ++i) {
                int el = (i & 3) + ((i >> 2) << 3) + (half << 2);
                atomicAdd(out + (size_t)ei[EE + ebw + g * 32 + el] * 32 + l, acc[g][i]);
            }
    }
}

extern "C" void kernel_launch(void* const* d_in, const int* in_sizes, int n_in,
                              void* d_out, int out_size, void* d_ws, size_t ws_size,
                              hipStream_t stream) {
    const float* x    = (const float*)d_in[0];
    const int*   ei   = (const int*)  d_in[1];
    const float* ea   = (const float*)d_in[2];
    const float* w1   = (const float*)d_in[3];
    const float* b1   = (const float*)d_in[4];
    const float* w2   = (const float*)d_in[5];
    const float* b2   = (const float*)d_in[6];
    const float* root = (const float*)d_in[7];
    const float* bias = (const float*)d_in[8];
    float* out = (float*)d_out;

    _Float16* w2p = (_Float16*)d_ws;                      // 262144 B
    _Float16* w1p = (_Float16*)((char*)d_ws + 262144);    //   8192 B
    _Float16* b2p = (_Float16*)((char*)d_ws + 270336);    //   2048 B

    prep_final_kernel<<<(NN * 32) / 256, 256, 0, stream>>>(
        x, root, bias, w1, w2, b2, w2p, w1p, b2p, out);

    edge_kernel<<<(EE + 511) / 512, 256, 0, stream>>>(
        x, ei, ea, b1, w2p, w1p, b2p, out);
}

// Round 11
// 241.448 us; speedup vs baseline: 1.0816x; 1.0816x over previous
//
#include <hip/hip_runtime.h>
#include <hip/hip_fp16.h>

// NNConv on MI355X. msg[E x 32] = Z[E x 4096] @ w2r[4096 x 32],
// Z[e, c*32+i] = h[e,c]*xs[e,i] built on the fly in fp16 A-fragments.
// Round 21: COLUMN-SPLIT for wave parallelism. R11-R20 eliminated
// atomics, launch count, B-load source, and MFMA density; every config
// ran 135-175 us at <=38% MfmaUtil because total waves were pinned at
// ~3125 (3/SIMD available, ~1.3 achieved) -- each wave's load/dep
// bubbles had no partner wave to hide behind. Same total work, twice
// the waves: wave = 64 edges x 64 columns (half the c-range), 12500
// waves (12.2/SIMD available, VGPR-capped 4/SIMD). Block = 2 waves on
// the SAME 64 edges (halves 0/1); wave 1 passes its partial acc via
// 8 KB LDS + one barrier so atomic count stays 12.8M; b2 applied once
// by wave 0. phase1 per wave covers only its own 2 slices. 64 | EE ->
// no tail. Reg-resident h via permlane32_swap (R19-verified mapping).
// ~127 VGPR at (128,2) cap 128. 2 launches (R17 scheme).

#define NN 25000
#define EE 400000

typedef _Float16 f16x8 __attribute__((ext_vector_type(8)));
typedef float    f32x16 __attribute__((ext_vector_type(16)));
typedef unsigned u32x2  __attribute__((ext_vector_type(2)));

// half-exchange: a = half0-lane values (rows base,base+1), y = half1-lane
// values (rows base+4,base+5), for every lane's own edge column (l&31).
__device__ __forceinline__ void swapHalves(unsigned u, int half,
                                           unsigned& a, unsigned& y) {
#if __has_builtin(__builtin_amdgcn_permlane32_swap)
    u32x2 rr = __builtin_amdgcn_permlane32_swap(u, u, false, false);
    a = rr.x;
    y = rr.y;
#else
    unsigned p = (unsigned)__shfl_xor((int)u, 32, 64);
    a = half ? p : u;
    y = half ? u : p;
#endif
}

// ---------------- launch 1: pack w1/w2/b2 + out = x@root + bias ----------------
__global__ __launch_bounds__(256) void prep_final_kernel(
    const float* __restrict__ x, const float* __restrict__ root,
    const float* __restrict__ bias,
    const float* __restrict__ w1, const float* __restrict__ w2,
    const float* __restrict__ b2,
    _Float16* __restrict__ w2p, _Float16* __restrict__ w1p, _Float16* __restrict__ b2p,
    float* __restrict__ out)
{
    const int t = blockIdx.x * 256 + threadIdx.x;

    if (t < 131072) {
        int j = t & 7, lane = (t >> 3) & 63, ih = (t >> 9) & 1, c = t >> 10;
        w2p[t] = (_Float16)w2[c * 1024 + (ih * 16 + ((lane >> 5) << 3) + j) * 32 + (lane & 31)];
    } else if (t < 135168) {
        int u = t - 131072;
        int j = u & 7, lane = (u >> 3) & 63, kk = (u >> 9) & 1, r = u >> 10;
        w1p[u] = (_Float16)w1[(kk * 16 + ((lane >> 5) << 3) + j) * 128 + r * 32 + (lane & 31)];
    } else if (t < 136192) {
        int u = t - 135168;
        int j = u & 7, lane = (u >> 3) & 63, ih = u >> 9;
        b2p[u] = (_Float16)b2[(ih * 16 + ((lane >> 5) << 3) + j) * 32 + (lane & 31)];
    }

    int n = t >> 5, o = t & 31;
    float acc = bias[o];
    const float* xr = x + (n << 5);
#pragma unroll
    for (int i = 0; i < 32; ++i)
        acc = fmaf(xr[i], root[(i << 5) + o], acc);
    out[t] = acc;
}

// ---------------- launch 2: edge kernel (col-split, 2 waves share 64 edges) ----------------
// 128 thr = 2 waves; block = 64 edges (2 groups of 32) x all 128 columns
// (wave w owns columns [64w, 64w+64)). grid 6250 exact.
__global__ __launch_bounds__(128, 2) void edge_kernel(
    const float*    __restrict__ x,
    const int*      __restrict__ ei,
    const float*    __restrict__ ea,
    const float*    __restrict__ b1,
    const _Float16* __restrict__ w2p,
    const _Float16* __restrict__ w1p,
    const _Float16* __restrict__ b2p,
    float* __restrict__ out)
{
    __shared__ __align__(16) float comb[64][32];   // 8 KB: wave1 partial acc

    const int t    = threadIdx.x;
    const int w    = t >> 6;           // col-half
    const int lane = t & 63;
    const int l    = lane & 31;
    const int half = lane >> 5;
    const int ebw  = blockIdx.x * 64;  // 64 * 6250 == EE, no tail

    union u8h { f16x8 v; __half2 h2[4]; };

    // ---- w2 B-columns read DIRECTLY from global (L2-resident, 256 KB) ----
    const f16x8* __restrict__ w2f = (const f16x8*)w2p;

    f16x8 BA[2], BB[2], BC[2], BD[2];              // 4-deep column buffers
    auto loadCol = [&](int j, f16x8 (&B)[2]) {
        const f16x8* p = w2f + (size_t)j * 128 + lane;
        B[0] = p[0];
        B[1] = p[64];
    };
    const int colBase = w * 64;
    loadCol(colBase + 0, BA); loadCol(colBase + 1, BB);
    loadCol(colBase + 2, BC); loadCol(colBase + 3, BD);

    // ---- persistent edge-attr fragments (fp16), 2 groups; read ONCE (16 VGPR) ----
    u8h eaf[2][2];
#pragma unroll
    for (int g = 0; g < 2; ++g)
#pragma unroll
        for (int kk = 0; kk < 2; ++kk) {
            const float* p = ea + (size_t)(ebw + g * 32 + l) * 32 + kk * 16 + half * 8;
            float4 a0 = *(const float4*)p;
            float4 a1 = *(const float4*)(p + 4);
            eaf[g][kk].h2[0] = __float22half2_rn(make_float2(a0.x, a0.y));
            eaf[g][kk].h2[1] = __float22half2_rn(make_float2(a0.z, a0.w));
            eaf[g][kk].h2[2] = __float22half2_rn(make_float2(a1.x, a1.y));
            eaf[g][kk].h2[3] = __float22half2_rn(make_float2(a1.z, a1.w));
        }

    // ---- gather xs rows (fp16 pairs) for 2 groups (16 VGPR) ----
    __half2 xs[2][8];
#pragma unroll
    for (int g = 0; g < 2; ++g) {
        int s = ei[ebw + g * 32 + l];
#pragma unroll
        for (int ih = 0; ih < 2; ++ih) {
            float4 a0 = *(const float4*)(x + s * 32 + ih * 16 + half * 8);
            float4 a1 = *(const float4*)(x + s * 32 + ih * 16 + half * 8 + 4);
            xs[g][ih*4+0] = __float22half2_rn(make_float2(a0.x, a0.y));
            xs[g][ih*4+1] = __float22half2_rn(make_float2(a0.z, a0.w));
            xs[g][ih*4+2] = __float22half2_rn(make_float2(a1.x, a1.y));
            xs[g][ih*4+3] = __float22half2_rn(make_float2(a1.z, a1.w));
        }
    }

    f32x16 acc[2];
#pragma unroll
    for (int g = 0; g < 2; ++g)
#pragma unroll
        for (int i = 0; i < 16; ++i) acc[g][i] = 0.f;

    // h slice own-half pairs (R19-verified layout): hpk[g][jj] = channels
    // (base(jj)+4*half, +1), base(jj) = (2jj&3) + ((2jj>>2)<<3).
    __half2 hpk[2][8];

    auto phase1 = [&](int r) {
        f16x8 w1f0 = *(const f16x8*)(w1p + ((r * 2 + 0) * 64 + lane) * 8);
        f16x8 w1f1 = *(const f16x8*)(w1p + ((r * 2 + 1) * 64 + lane) * 8);
#pragma unroll
        for (int g = 0; g < 2; ++g) {
            f32x16 h;
#pragma unroll
            for (int i = 0; i < 16; ++i) h[i] = 0.f;
            h = __builtin_amdgcn_mfma_f32_32x32x16_f16(w1f0, eaf[g][0].v, h, 0, 0, 0);
            h = __builtin_amdgcn_mfma_f32_32x32x16_f16(w1f1, eaf[g][1].v, h, 0, 0, 0);
#pragma unroll
            for (int jj = 0; jj < 8; ++jj) {
                int i0 = 2 * jj;
                int r0 = (i0 & 3) + ((i0 >> 2) << 3) + (half << 2);  // verified C/D map
                hpk[g][jj] = __float22half2_rn(make_float2(
                    fmaxf(h[i0]     + b1[r * 32 + r0],     0.f),
                    fmaxf(h[i0 + 1] + b1[r * 32 + r0 + 1], 0.f)));
            }
        }
    };

    __half2 Ac[2][2], Yc[2][2];        // swap cache (R19-verified mapping)

    // one column: d = lane-uniform channel scalar per group, 4 MFMAs
    auto colMFMA = [&](const __half2 (&C)[2][2], int dd, bool hi,
                       const f16x8 (&B)[2]) {
        __half2 d0 = __half2half2(hi ? __high2half(C[0][dd]) : __low2half(C[0][dd]));
        __half2 d1 = __half2half2(hi ? __high2half(C[1][dd]) : __low2half(C[1][dd]));
#pragma unroll
        for (int ih = 0; ih < 2; ++ih) {
            u8h A;
#pragma unroll
            for (int p = 0; p < 4; ++p)
                A.h2[p] = __hmul2(d0, xs[0][ih * 4 + p]);     // v_pk_mul_f16
            acc[0] = __builtin_amdgcn_mfma_f32_32x32x16_f16(A.v, B[ih], acc[0], 0, 0, 0);
#pragma unroll
            for (int p = 0; p < 4; ++p)
                A.h2[p] = __hmul2(d1, xs[1][ih * 4 + p]);
            acc[1] = __builtin_amdgcn_mfma_f32_32x32x16_f16(A.v, B[ih], acc[1], 0, 0, 0);
        }
    };

    // ---- main loop: 2 slices per wave; linear cols, 3-col prefetch.
    // Max overread (w=1, last prefetches): cols 128-131 -> w1p region
    // (valid workspace, values unused). ----
#pragma unroll 1
    for (int rr = 0; rr < 2; ++rr) {
        const int r = w * 2 + rr;
        phase1(r);
#pragma unroll
        for (int q = 0; q < 8; ++q) {
            const int j = r * 32 + q * 4;
            if ((q & 1) == 0) {
#pragma unroll
                for (int g = 0; g < 2; ++g)
#pragma unroll
                    for (int dd = 0; dd < 2; ++dd) {
                        unsigned a, y;
                        swapHalves(__builtin_bit_cast(unsigned, hpk[g][q + dd]),
                                   half, a, y);
                        Ac[g][dd] = __builtin_bit_cast(__half2, a);
                        Yc[g][dd] = __builtin_bit_cast(__half2, y);
                    }
                colMFMA(Ac, 0, false, BA); loadCol(j + 4, BA);
                colMFMA(Ac, 0, true,  BB); loadCol(j + 5, BB);
                colMFMA(Ac, 1, false, BC); loadCol(j + 6, BC);
                colMFMA(Ac, 1, true,  BD); loadCol(j + 7, BD);
            } else {
                colMFMA(Yc, 0, false, BA); loadCol(j + 4, BA);
                colMFMA(Yc, 0, true,  BB); loadCol(j + 5, BB);
                colMFMA(Yc, 1, false, BC); loadCol(j + 6, BC);
                colMFMA(Yc, 1, true,  BD); loadCol(j + 7, BD);
            }
        }
    }

    // ---- combine: wave 1 -> LDS, one barrier, wave 0 reduces ----
    if (w == 1) {
#pragma unroll
        for (int g = 0; g < 2; ++g)
#pragma unroll
            for (int i = 0; i < 16; ++i)
                comb[lane][g * 16 + i] = acc[g][i];
    }
    __syncthreads();
    if (w == 0) {
#pragma unroll
        for (int g = 0; g < 2; ++g)
#pragma unroll
            for (int i = 0; i < 16; ++i)
                acc[g][i] += comb[lane][g * 16 + i];

        // b2 contribution ONCE: extra K-step with h == 1 (A-fragment = xs)
#pragma unroll
        for (int ih = 0; ih < 2; ++ih) {
            f16x8 bfr = *(const f16x8*)(b2p + (ih * 64 + lane) * 8);
#pragma unroll
            for (int g = 0; g < 2; ++g) {
                u8h A;
#pragma unroll
                for (int p = 0; p < 4; ++p) A.h2[p] = xs[g][ih * 4 + p];
                acc[g] = __builtin_amdgcn_mfma_f32_32x32x16_f16(A.v, bfr, acc[g], 0, 0, 0);
            }
        }

        // scatter-add into out (base written by launch 1)
#pragma unroll
        for (int g = 0; g < 2; ++g)
#pragma unroll
            for (int i = 0; i < 16; ++i) {
                int el = (i & 3) + ((i >> 2) << 3) + (half << 2);
                atomicAdd(out + (size_t)ei[EE + ebw + g * 32 + el] * 32 + l, acc[g][i]);
            }
    }
}

extern "C" void kernel_launch(void* const* d_in, const int* in_sizes, int n_in,
                              void* d_out, int out_size, void* d_ws, size_t ws_size,
                              hipStream_t stream) {
    const float* x    = (const float*)d_in[0];
    const int*   ei   = (const int*)  d_in[1];
    const float* ea   = (const float*)d_in[2];
    const float* w1   = (const float*)d_in[3];
    const float* b1   = (const float*)d_in[4];
    const float* w2   = (const float*)d_in[5];
    const float* b2   = (const float*)d_in[6];
    const float* root = (const float*)d_in[7];
    const float* bias = (const float*)d_in[8];
    float* out = (float*)d_out;

    _Float16* w2p = (_Float16*)d_ws;                      // 262144 B
    _Float16* w1p = (_Float16*)((char*)d_ws + 262144);    //   8192 B
    _Float16* b2p = (_Float16*)((char*)d_ws + 270336);    //   2048 B
    // (edge kernel overread headroom: may touch up to ~270.4 KB of d_ws)

    prep_final_kernel<<<(NN * 32) / 256, 256, 0, stream>>>(
        x, root, bias, w1, w2, b2, w2p, w1p, b2p, out);

    edge_kernel<<<EE / 64, 128, 0, stream>>>(
        x, ei, ea, b1, w2p, w1p, b2p, out);
}